// Round 13
// baseline (114.390 us; speedup 1.0000x reference)
//
#include <hip/hip_runtime.h>

// KNRM forward, MI355X (gfx950). R12.
// R11 post-mortem: bytes/granules/occupancy all moved, dur ~flat; invariant is
// ~1us wall per apply_pair. VGPR_Count=44 < sp[21] packed (42) + Bq(16) + C(4):
// the persistent accumulator CANNOT be in arch VGPRs -> AGPR/scratch shuttle
// around every ladder op (explains VALUBusy 67-72% everywhere). R12: scalar
// sp[21] (21 regs) with DEFERRED ladder constants (power sums t0*R^j in-loop;
// e^{-j(j+-1)/2} applied once per lane at reduction -- overflow-checked:
// max term e^44.9, sum < 1e22 << f32 max). Live set ~60 regs -> fits 64-reg/
// 8-wave target, zero shuttle. Staging/structure byte-identical to R11.

typedef __attribute__((ext_vector_type(8))) _Float16 f16x8;
typedef __attribute__((ext_vector_type(4))) float f32x4;
typedef __attribute__((ext_vector_type(2))) float f32x2;

__device__ __forceinline__ unsigned short h2s(_Float16 h) {
    return __builtin_bit_cast(unsigned short, h);
}

// ---- precompute: normalized fp16 table, row-major [vocab][128] (256B/row) ----
__global__ __launch_bounds__(256)
void norm_split_kernel(const float* __restrict__ emb,
                       unsigned short* __restrict__ tab, int vocab)
{
    const int row = blockIdx.x * 8 + (threadIdx.x >> 5);
    if (row >= vocab) return;
    const int ln = threadIdx.x & 31;
    const float4 v = *reinterpret_cast<const float4*>(emb + (size_t)row * 128 + ln * 4);
    float ss = v.x*v.x + v.y*v.y + v.z*v.z + v.w*v.w;
    #pragma unroll
    for (int m = 16; m >= 1; m >>= 1) ss += __shfl_xor(ss, m);   // 32-lane row reduce
    const float rn = 1.0f / (sqrtf(ss) + 1e-13f);                // reference eps
    const unsigned short h0 = h2s((_Float16)(v.x * rn));
    const unsigned short h1 = h2s((_Float16)(v.y * rn));
    const unsigned short h2 = h2s((_Float16)(v.z * rn));
    const unsigned short h3 = h2s((_Float16)(v.w * rn));
    *reinterpret_cast<uint2*>(tab + (size_t)row * 128 + ln * 4) =
        make_uint2((unsigned)h0 | ((unsigned)h1 << 16), (unsigned)h2 | ((unsigned)h3 << 16));
}

// ---- global_load_lds: 16B/lane, linear LDS dest (base + lane*16) ----
__device__ __forceinline__ void glds16(const unsigned short* g, unsigned short* l) {
    __builtin_amdgcn_global_load_lds((const __attribute__((address_space(1))) void*)g,
                                     (__attribute__((address_space(3))) void*)l, 16, 0, 0);
}

// Stage one 16-row chunk (wave w: rows 4w..4w+3 -> ONE glds16).
// Swizzle folded into per-lane GLOBAL address: slot s holds group s^r.
__device__ __forceinline__ void stage_d16(const unsigned short* __restrict__ tab,
                                          const int* __restrict__ ids, int base,
                                          unsigned short* __restrict__ db,
                                          int w, int l)
{
    const int r   = 4*w + (l >> 4);                  // buffer row 0..15
    const int id  = ids[base + r];                   // LDS broadcast read
    const int gsw = ((l & 15) ^ r) << 3;             // swizzled elem offset in row
    glds16(tab + (size_t)id * 128 + gsw, db + 4*w * 128);
}

// Stage q: wave w fills one ring buffer with its 16 q rows (4 glds16).
__device__ __forceinline__ void stage_q16(const unsigned short* __restrict__ tab,
                                          const int* __restrict__ qids,
                                          unsigned short* __restrict__ db,
                                          int w, int l)
{
    #pragma unroll
    for (int j = 0; j < 4; j++) {
        const int r   = 4*j + (l >> 4);
        const int id  = qids[16*w + r];
        const int gsw = ((l & 15) ^ r) << 3;
        glds16(tab + (size_t)id * 128 + gsw, db + 4*j * 128);
    }
}

// Deferred ladder constants (applied once per lane at reduction):
// sp[10+j] holds Sum t0*R^j  -> true k-sum = sp * e^{-j(j+1)/2}
// sp[10-j] holds Sum t0*R^-j -> true k-sum = sp * e^{-j(j-1)/2}
__device__ __constant__ float KC[21] = {
    2.8625185805e-20f, 2.3195228302e-16f, 6.9144001069e-13f, 7.5825604279e-10f,
    3.0590232050e-7f,  4.5399929762e-5f,  2.4787521767e-3f,  4.9787068368e-2f,
    3.6787944117e-1f,  1.0f,              1.0f,              3.6787944117e-1f,
    4.9787068368e-2f,  2.4787521767e-3f,  4.5399929762e-5f,  3.0590232050e-7f,
    7.5825604279e-10f, 6.9144001069e-13f, 2.3195228302e-16f, 2.8625185805e-20f,
    1.0f
};

// 21 kernel power-sum contributions of an element PAIR (m0,m1); sp scalar.
__device__ __forceinline__ void apply_pair_s(float m0, float m1, float (&sp)[21]) {
    const f32x2 m2 = {m0, m1};
    const f32x2 dm = m2 - 0.05f;
    const f32x2 ta = (dm * dm) * -72.13475204444817f;            // -50*log2e*(m-.05)^2
    const f32x2 x2 = m2 * 14.426950408889634f;                   // 10*log2e*m
    const f32x2 t0 = { __builtin_amdgcn_exp2f(ta[0]), __builtin_amdgcn_exp2f(ta[1]) };
    const f32x2 R  = { __builtin_amdgcn_exp2f(x2[0]), __builtin_amdgcn_exp2f(x2[1]) };
    const f32x2 Ri = { __builtin_amdgcn_exp2f(-x2[0]), __builtin_amdgcn_exp2f(-x2[1]) };
    sp[10] += t0[0] + t0[1];
    f32x2 tu = t0;
    tu *= R;  sp[11] += tu[0] + tu[1];
    tu *= R;  sp[12] += tu[0] + tu[1];
    tu *= R;  sp[13] += tu[0] + tu[1];
    tu *= R;  sp[14] += tu[0] + tu[1];
    tu *= R;  sp[15] += tu[0] + tu[1];
    tu *= R;  sp[16] += tu[0] + tu[1];
    tu *= R;  sp[17] += tu[0] + tu[1];
    tu *= R;  sp[18] += tu[0] + tu[1];
    tu *= R;  sp[19] += tu[0] + tu[1];
    f32x2 td = t0;
    td *= Ri; sp[9] += td[0] + td[1];
    td *= Ri; sp[8] += td[0] + td[1];
    td *= Ri; sp[7] += td[0] + td[1];
    td *= Ri; sp[6] += td[0] + td[1];
    td *= Ri; sp[5] += td[0] + td[1];
    td *= Ri; sp[4] += td[0] + td[1];
    td *= Ri; sp[3] += td[0] + td[1];
    td *= Ri; sp[2] += td[0] + td[1];
    td *= Ri; sp[1] += td[0] + td[1];
    td *= Ri; sp[0] += td[0] + td[1];
    const f32x2 e  = m2 - 1.0f;                                  // exact-match (sigma=1e-3)
    const f32x2 ea = (e * e) * -721347.5204444817f;
    sp[20] += __builtin_amdgcn_exp2f(ea[0]) + __builtin_amdgcn_exp2f(ea[1]);
}

// ---- main kernel: one block per (batch, pass); ring-6 of fp16 16-row chunks ----
__global__ __launch_bounds__(256, 2)
void knrm_main(const int* __restrict__ q1, const int* __restrict__ d1,
               const int* __restrict__ q2, const int* __restrict__ d2,
               const unsigned short* __restrict__ tab,
               float* __restrict__ kmws)
{
    __shared__ unsigned short buf[6][16*128];  // 4KB each (fp16 rows)
    __shared__ int   sh_ids[256];
    __shared__ float KMpart[4][21];

    const int tid = threadIdx.x;
    const int bb  = blockIdx.x >> 1;
    const int p   = blockIdx.x & 1;
    const int w   = tid >> 6;     // wave 0..3 -> q rows 16w..16w+15
    const int l   = tid & 63;
    const int lr  = l & 15;       // MFMA row (A) / col=q (B,C)
    const int lh  = l >> 4;       // k-group

    const int* qids = (p == 0 ? q1 : q2) + bb * 64;
    const int* dids = (p == 0 ? d1 : d2) + bb * 256;

    sh_ids[tid] = dids[tid];
    stage_q16(tab, qids, buf[w], w, l);              // buf w = wave w's q rows
    asm volatile("s_waitcnt vmcnt(0) lgkmcnt(0)" ::: "memory");
    __builtin_amdgcn_s_barrier();                    // q + sh_ids visible to all

    // Hoist B (q-side) fragments to registers for the whole pass.
    f16x8 Bq[4];
    #pragma unroll
    for (int ks = 0; ks < 4; ks++) {
        const int off = lr*128 + (((ks*4 + lh) ^ lr) << 3);
        Bq[ks] = *reinterpret_cast<const f16x8*>(&buf[w][off]);
    }
    asm volatile("s_waitcnt lgkmcnt(0)" ::: "memory");   // my B reads landed
    __builtin_amdgcn_s_barrier();                        // all waves done reading q

    float sp[21];
    #pragma unroll
    for (int i = 0; i < 21; i++) sp[i] = 0.0f;

    // Prologue: chunks 0..4 in flight (5 loads/wave outstanding).
    stage_d16(tab, sh_ids, 0,  buf[0], w, l);
    stage_d16(tab, sh_ids, 16, buf[1], w, l);
    stage_d16(tab, sh_ids, 32, buf[2], w, l);
    stage_d16(tab, sh_ids, 48, buf[3], w, l);
    stage_d16(tab, sh_ids, 64, buf[4], w, l);

    for (int c = 0; c < 16; c++) {
        // Wait for my chunk-c load only (up to 4 later chunks stay in flight).
        if (c <= 11)      asm volatile("s_waitcnt vmcnt(4)" ::: "memory");
        else if (c == 12) asm volatile("s_waitcnt vmcnt(3)" ::: "memory");
        else if (c == 13) asm volatile("s_waitcnt vmcnt(2)" ::: "memory");
        else if (c == 14) asm volatile("s_waitcnt vmcnt(1)" ::: "memory");
        else              asm volatile("s_waitcnt vmcnt(0)" ::: "memory");
        __builtin_amdgcn_s_barrier();                // chunk c staged by all waves
        // (single barrier: refill slot (c+5)%6 == (c-1)%6 was freed by every
        //  wave before it passed THIS barrier)

        const unsigned short* cb = buf[c % 6];
        f32x4 C = {0.f,0.f,0.f,0.f};
        #pragma unroll
        for (int ks = 0; ks < 4; ks++) {
            const int o = lr*128 + (((ks*4 + lh) ^ lr) << 3);
            const f16x8 A = *reinterpret_cast<const f16x8*>(cb + o);
            C = __builtin_amdgcn_mfma_f32_16x16x32_f16(A, Bq[ks], C, 0, 0, 0);
        }
        apply_pair_s(C[0], C[1], sp);
        apply_pair_s(C[2], C[3], sp);

        if (c <= 10)                                 // refill freed slot with chunk c+5
            stage_d16(tab, sh_ids, (c + 5) * 16, buf[(c + 5) % 6], w, l);
    }

    // Reduction: apply deferred constant, q-col sum (xor16,32) -> log1p ->
    // 16-group sum (xor1..8) -> per-wave partial KM.
    #pragma unroll
    for (int i = 0; i < 21; i++) {
        float s = sp[i] * KC[i];
        s += __shfl_xor(s, 16);
        s += __shfl_xor(s, 32);
        float t = log1pf(s);
        t += __shfl_xor(t, 1);
        t += __shfl_xor(t, 2);
        t += __shfl_xor(t, 4);
        t += __shfl_xor(t, 8);
        if (l == 0) KMpart[w][i] = t;
    }
    __syncthreads();
    if (tid < 21)
        kmws[blockIdx.x * 21 + tid] = KMpart[0][tid] + KMpart[1][tid]
                                    + KMpart[2][tid] + KMpart[3][tid];
}

// ---- tiny MLP kernel: one block per batch element ----
__global__ __launch_bounds__(64)
void mlp_kernel(const float* __restrict__ kmws,
                const float* __restrict__ W1, const float* __restrict__ b1,
                const float* __restrict__ W2, const float* __restrict__ b2,
                const float* __restrict__ W3, const float* __restrict__ b3,
                float* __restrict__ out)
{
    __shared__ float KMs[2][21], x1s[2][10], x2s[2][5];
    const int tid = threadIdx.x;
    const int bb  = blockIdx.x;
    if (tid < 42) KMs[tid / 21][tid % 21] = kmws[(bb * 2 + tid / 21) * 21 + (tid % 21)];
    __syncthreads();
    if (tid < 10) {
        for (int p = 0; p < 2; p++) {
            float acc = b1[tid];
            #pragma unroll
            for (int i = 0; i < 21; i++) acc = fmaf(fmaxf(KMs[p][i], 0.0f), W1[i*10 + tid], acc);
            x1s[p][tid] = acc;
        }
    }
    __syncthreads();
    if (tid < 5) {
        for (int p = 0; p < 2; p++) {
            float acc = b2[tid];
            #pragma unroll
            for (int i = 0; i < 10; i++) acc = fmaf(fmaxf(x1s[p][i], 0.0f), W2[i*5 + tid], acc);
            x2s[p][tid] = acc;
        }
    }
    __syncthreads();
    if (tid == 0) {
        float lv[2];
        for (int p = 0; p < 2; p++) {
            float acc = b3[0];
            #pragma unroll
            for (int i = 0; i < 5; i++) acc = fmaf(fmaxf(x2s[p][i], 0.0f), W3[i], acc);
            lv[p] = acc;
        }
        out[bb] = 1.0f / (1.0f + expf(lv[1] - lv[0]));   // sigmoid(l1 - l2)
    }
}

// ---- fallback (ws too small): self-contained f32-gather kernel (bf16-split) ----
typedef __attribute__((ext_vector_type(8))) short bf16x8;
__device__ __forceinline__ unsigned short f2bf(float f) {
    unsigned u = __float_as_uint(f);
    u += 0x7fffu + ((u >> 16) & 1u);
    return (unsigned short)(u >> 16);
}
__device__ __forceinline__ float bf2f(unsigned short h) {
    return __uint_as_float(((unsigned)h) << 16);
}
__device__ __forceinline__ void stage_f32(const float* __restrict__ emb,
                                          const int* __restrict__ ids,
                                          unsigned short* __restrict__ hi,
                                          unsigned short* __restrict__ lo,
                                          int tid)
{
    const int lg = tid >> 5;
    const int ln = tid & 31;
    #pragma unroll
    for (int i = 0; i < 4; i++) {
        const int row = i * 8 + lg;
        const int id  = ids[row];
        const float4 v = *reinterpret_cast<const float4*>(emb + (size_t)id * 128 + ln * 4);
        float ss = v.x*v.x + v.y*v.y + v.z*v.z + v.w*v.w;
        #pragma unroll
        for (int m = 16; m >= 1; m >>= 1) ss += __shfl_xor(ss, m);
        const float rn = 1.0f / (sqrtf(ss) + 1e-13f);
        const float f0 = v.x*rn, f1 = v.y*rn, f2 = v.z*rn, f3 = v.w*rn;
        const unsigned short h0 = f2bf(f0), h1 = f2bf(f1), h2 = f2bf(f2), h3 = f2bf(f3);
        const unsigned short g0 = f2bf(f0 - bf2f(h0)), g1 = f2bf(f1 - bf2f(h1));
        const unsigned short g2 = f2bf(f2 - bf2f(h2)), g3 = f2bf(f3 - bf2f(h3));
        const int off = row*128 + (((ln >> 1) ^ (row & 15)) << 3) + ((ln & 1) << 2);
        *reinterpret_cast<uint2*>(hi + off) =
            make_uint2((unsigned)h0 | ((unsigned)h1 << 16), (unsigned)h2 | ((unsigned)h3 << 16));
        *reinterpret_cast<uint2*>(lo + off) =
            make_uint2((unsigned)g0 | ((unsigned)g1 << 16), (unsigned)g2 | ((unsigned)g3 << 16));
    }
}
#define MFMB(a, b, c) __builtin_amdgcn_mfma_f32_16x16x32_bf16((a), (b), (c), 0, 0, 0)

__global__ __launch_bounds__(256, 2)
void knrm_fallback(const int* __restrict__ q1, const int* __restrict__ d1,
                   const int* __restrict__ q2, const int* __restrict__ d2,
                   const float* __restrict__ emb,
                   const float* __restrict__ W1, const float* __restrict__ b1,
                   const float* __restrict__ W2, const float* __restrict__ b2,
                   const float* __restrict__ W3, const float* __restrict__ b3,
                   float* __restrict__ out)
{
    __shared__ unsigned short bh[2][32*128], bl[2][32*128];
    __shared__ float KMpart[2][4][21];
    __shared__ float x1s[2][10], x2s[2][5];
    const int tid = threadIdx.x;
    const int bb  = blockIdx.x;
    const int w   = tid >> 6;
    const int l   = tid & 63;
    const int lr  = l & 15;
    const int lh  = l >> 4;

    for (int p = 0; p < 2; p++) {
        const int* qids = (p == 0 ? q1 : q2) + bb * 64;
        const int* dids = (p == 0 ? d1 : d2) + bb * 256;
        stage_f32(emb, qids,      bh[0], bl[0], tid);
        stage_f32(emb, qids + 32, bh[1], bl[1], tid);
        __syncthreads();
        bf16x8 Bh[4], Bl[4];
        const int qb = w >> 1;
        const int qr = (w * 16 + lr) & 31;
        #pragma unroll
        for (int ks = 0; ks < 4; ks++) {
            const int off = qr*128 + (((ks*4 + lh) ^ lr) << 3);
            Bh[ks] = *reinterpret_cast<const bf16x8*>(&bh[qb][off]);
            Bl[ks] = *reinterpret_cast<const bf16x8*>(&bl[qb][off]);
        }
        __syncthreads();
        float sp[21];
        #pragma unroll
        for (int i = 0; i < 21; i++) sp[i] = 0.0f;
        for (int c = 0; c < 8; c++) {
            stage_f32(emb, dids + c * 32, bh[c & 1], bl[c & 1], tid);
            __syncthreads();
            const unsigned short* ch = bh[c & 1];
            const unsigned short* cl = bl[c & 1];
            f32x4 C0 = {0.f,0.f,0.f,0.f}, C1 = {0.f,0.f,0.f,0.f};
            #pragma unroll
            for (int ks = 0; ks < 4; ks++) {
                const int o0 = lr*128        + (((ks*4 + lh) ^ lr) << 3);
                const int o1 = (16 + lr)*128 + (((ks*4 + lh) ^ lr) << 3);
                const bf16x8 A0h = *reinterpret_cast<const bf16x8*>(ch + o0);
                const bf16x8 A0l = *reinterpret_cast<const bf16x8*>(cl + o0);
                const bf16x8 A1h = *reinterpret_cast<const bf16x8*>(ch + o1);
                const bf16x8 A1l = *reinterpret_cast<const bf16x8*>(cl + o1);
                C0 = MFMB(A0h, Bh[ks], C0); C1 = MFMB(A1h, Bh[ks], C1);
                C0 = MFMB(A0h, Bl[ks], C0); C1 = MFMB(A1h, Bl[ks], C1);
                C0 = MFMB(A0l, Bh[ks], C0); C1 = MFMB(A1l, Bh[ks], C1);
            }
            apply_pair_s(C0[0], C0[1], sp); apply_pair_s(C0[2], C0[3], sp);
            apply_pair_s(C1[0], C1[1], sp); apply_pair_s(C1[2], C1[3], sp);
            __syncthreads();
        }
        #pragma unroll
        for (int i = 0; i < 21; i++) {
            float s = sp[i] * KC[i];
            s += __shfl_xor(s, 16);
            s += __shfl_xor(s, 32);
            float t = log1pf(s);
            t += __shfl_xor(t, 1);
            t += __shfl_xor(t, 2);
            t += __shfl_xor(t, 4);
            t += __shfl_xor(t, 8);
            if (l == 0) KMpart[p][w][i] = t;
        }
    }
    __syncthreads();
    if (tid < 10) {
        for (int p = 0; p < 2; p++) {
            float acc = b1[tid];
            #pragma unroll
            for (int i = 0; i < 21; i++) {
                const float km = KMpart[p][0][i] + KMpart[p][1][i]
                               + KMpart[p][2][i] + KMpart[p][3][i];
                acc = fmaf(fmaxf(km, 0.0f), W1[i*10 + tid], acc);
            }
            x1s[p][tid] = acc;
        }
    }
    __syncthreads();
    if (tid < 5) {
        for (int p = 0; p < 2; p++) {
            float acc = b2[tid];
            #pragma unroll
            for (int i = 0; i < 10; i++) acc = fmaf(fmaxf(x1s[p][i], 0.0f), W2[i*5 + tid], acc);
            x2s[p][tid] = acc;
        }
    }
    __syncthreads();
    if (tid == 0) {
        float lv[2];
        for (int p = 0; p < 2; p++) {
            float acc = b3[0];
            #pragma unroll
            for (int i = 0; i < 5; i++) acc = fmaf(fmaxf(x2s[p][i], 0.0f), W3[i], acc);
            lv[p] = acc;
        }
        out[bb] = 1.0f / (1.0f + expf(lv[1] - lv[0]));
    }
}

extern "C" void kernel_launch(void* const* d_in, const int* in_sizes, int n_in,
                              void* d_out, int out_size, void* d_ws, size_t ws_size,
                              hipStream_t stream)
{
    const int*   q1  = (const int*)  d_in[0];
    const int*   d1  = (const int*)  d_in[1];
    const int*   q2  = (const int*)  d_in[2];
    const int*   d2  = (const int*)  d_in[3];
    const float* emb = (const float*)d_in[4];
    const float* W1  = (const float*)d_in[5];
    const float* b1  = (const float*)d_in[6];
    const float* W2  = (const float*)d_in[7];
    const float* b2  = (const float*)d_in[8];
    const float* W3  = (const float*)d_in[9];
    const float* b3  = (const float*)d_in[10];
    float* out = (float*)d_out;
    (void)n_in;

    const int    vocab = in_sizes[4] / 128;
    const size_t tabsz = (size_t)vocab * 128 * 2;        // fp16 table bytes
    const size_t kmsz  = (size_t)out_size * 2 * 21 * 4;  // KM partials
    const size_t need  = tabsz + kmsz;

    if (ws_size >= need) {
        unsigned short* tab = (unsigned short*)d_ws;
        float* kmws = (float*)((char*)d_ws + tabsz);
        norm_split_kernel<<<(vocab + 7) / 8, 256, 0, stream>>>(emb, tab, vocab);
        knrm_main<<<out_size * 2, 256, 0, stream>>>(q1, d1, q2, d2, tab, kmws);
        mlp_kernel<<<out_size, 64, 0, stream>>>(kmws, W1, b1, W2, b2, W3, b3, out);
    } else {
        knrm_fallback<<<out_size, 256, 0, stream>>>(q1, d1, q2, d2, emb,
                                                    W1, b1, W2, b2, W3, b3, out);
    }
}

// Round 15
// 104.550 us; speedup vs baseline: 1.0941x; 1.0941x over previous
//
#include <hip/hip_runtime.h>

// KNRM forward, MI355X (gfx950). R14.
// R13 (inline-asm ladder) FAILED correctness (0.1875) -- asm/allocator
// interaction, reverted. R14 = safe intersection of two PASSING kernels:
// R11 structure+packed ladder (93.8us main) ⊕ R12's deferred ladder constants
// (verified 0.0039). Every per-kernel accumulate is now a bare v_pk_add_f32
// (sp[i] += tu): no fma third operand, no f32x2 constant splats (VOP3 can't
// take literals -> R11 materialized 18 packed constants in the hot block).
// Constants e^{-j(j+-1)/2} applied once per lane at reduction via KC[].
// Staging identical to R11: fp16 table, ring-6 of 16-row chunks, counted
// vmcnt, single barrier/chunk.

typedef __attribute__((ext_vector_type(8))) _Float16 f16x8;
typedef __attribute__((ext_vector_type(4))) float f32x4;
typedef __attribute__((ext_vector_type(2))) float f32x2;

__device__ __forceinline__ unsigned short h2s(_Float16 h) {
    return __builtin_bit_cast(unsigned short, h);
}

// ---- precompute: normalized fp16 table, row-major [vocab][128] (256B/row) ----
__global__ __launch_bounds__(256)
void norm_split_kernel(const float* __restrict__ emb,
                       unsigned short* __restrict__ tab, int vocab)
{
    const int row = blockIdx.x * 8 + (threadIdx.x >> 5);
    if (row >= vocab) return;
    const int ln = threadIdx.x & 31;
    const float4 v = *reinterpret_cast<const float4*>(emb + (size_t)row * 128 + ln * 4);
    float ss = v.x*v.x + v.y*v.y + v.z*v.z + v.w*v.w;
    #pragma unroll
    for (int m = 16; m >= 1; m >>= 1) ss += __shfl_xor(ss, m);   // 32-lane row reduce
    const float rn = 1.0f / (sqrtf(ss) + 1e-13f);                // reference eps
    const unsigned short h0 = h2s((_Float16)(v.x * rn));
    const unsigned short h1 = h2s((_Float16)(v.y * rn));
    const unsigned short h2 = h2s((_Float16)(v.z * rn));
    const unsigned short h3 = h2s((_Float16)(v.w * rn));
    *reinterpret_cast<uint2*>(tab + (size_t)row * 128 + ln * 4) =
        make_uint2((unsigned)h0 | ((unsigned)h1 << 16), (unsigned)h2 | ((unsigned)h3 << 16));
}

// ---- global_load_lds: 16B/lane, linear LDS dest (base + lane*16) ----
__device__ __forceinline__ void glds16(const unsigned short* g, unsigned short* l) {
    __builtin_amdgcn_global_load_lds((const __attribute__((address_space(1))) void*)g,
                                     (__attribute__((address_space(3))) void*)l, 16, 0, 0);
}

// Stage one 16-row chunk (wave w: rows 4w..4w+3 -> ONE glds16).
// Swizzle folded into per-lane GLOBAL address: slot s holds group s^r.
__device__ __forceinline__ void stage_d16(const unsigned short* __restrict__ tab,
                                          const int* __restrict__ ids, int base,
                                          unsigned short* __restrict__ db,
                                          int w, int l)
{
    const int r   = 4*w + (l >> 4);                  // buffer row 0..15
    const int id  = ids[base + r];                   // LDS broadcast read
    const int gsw = ((l & 15) ^ r) << 3;             // swizzled elem offset in row
    glds16(tab + (size_t)id * 128 + gsw, db + 4*w * 128);
}

// Stage q: wave w fills one ring buffer with its 16 q rows (4 glds16).
__device__ __forceinline__ void stage_q16(const unsigned short* __restrict__ tab,
                                          const int* __restrict__ qids,
                                          unsigned short* __restrict__ db,
                                          int w, int l)
{
    #pragma unroll
    for (int j = 0; j < 4; j++) {
        const int r   = 4*j + (l >> 4);
        const int id  = qids[16*w + r];
        const int gsw = ((l & 15) ^ r) << 3;
        glds16(tab + (size_t)id * 128 + gsw, db + 4*j * 128);
    }
}

// Deferred ladder constants (applied once per lane at reduction):
// sp[10+j] holds Sum t0*R^j  -> true k-sum = sp * e^{-j(j+1)/2}
// sp[10-j] holds Sum t0*R^-j -> true k-sum = sp * e^{-j(j-1)/2}
__device__ __constant__ float KC[21] = {
    2.8625185805e-20f, 2.3195228302e-16f, 6.9144001069e-13f, 7.5825604279e-10f,
    3.0590232050e-7f,  4.5399929762e-5f,  2.4787521767e-3f,  4.9787068368e-2f,
    3.6787944117e-1f,  1.0f,              1.0f,              3.6787944117e-1f,
    4.9787068368e-2f,  2.4787521767e-3f,  4.5399929762e-5f,  3.0590232050e-7f,
    7.5825604279e-10f, 6.9144001069e-13f, 2.3195228302e-16f, 2.8625185805e-20f,
    1.0f
};

// 21 kernel power-sum contributions of an element PAIR (m0,m1); sp[i] packed.
// Pure add ladder: tu chain holds t0*R^j, accumulate with v_pk_add (no consts).
__device__ __forceinline__ void apply_pair(float m0, float m1, f32x2 (&sp)[21]) {
    const f32x2 m2 = {m0, m1};
    const f32x2 dm = m2 - 0.05f;
    const f32x2 ta = (dm * dm) * -72.13475204444817f;            // -50*log2e*(m-.05)^2
    const f32x2 x2 = m2 * 14.426950408889634f;                   // 10*log2e*m
    const f32x2 t0 = { __builtin_amdgcn_exp2f(ta[0]), __builtin_amdgcn_exp2f(ta[1]) };
    const f32x2 R  = { __builtin_amdgcn_exp2f(x2[0]), __builtin_amdgcn_exp2f(x2[1]) };
    const f32x2 Ri = { __builtin_amdgcn_exp2f(-x2[0]), __builtin_amdgcn_exp2f(-x2[1]) };
    sp[10] += t0;
    f32x2 tu = t0;
    tu *= R;  sp[11] += tu;
    tu *= R;  sp[12] += tu;
    tu *= R;  sp[13] += tu;
    tu *= R;  sp[14] += tu;
    tu *= R;  sp[15] += tu;
    tu *= R;  sp[16] += tu;
    tu *= R;  sp[17] += tu;
    tu *= R;  sp[18] += tu;
    tu *= R;  sp[19] += tu;
    f32x2 td = t0;
    td *= Ri; sp[9] += td;
    td *= Ri; sp[8] += td;
    td *= Ri; sp[7] += td;
    td *= Ri; sp[6] += td;
    td *= Ri; sp[5] += td;
    td *= Ri; sp[4] += td;
    td *= Ri; sp[3] += td;
    td *= Ri; sp[2] += td;
    td *= Ri; sp[1] += td;
    td *= Ri; sp[0] += td;
    const f32x2 e  = m2 - 1.0f;                                  // exact-match (sigma=1e-3)
    const f32x2 ea = (e * e) * -721347.5204444817f;
    const f32x2 ex = { __builtin_amdgcn_exp2f(ea[0]), __builtin_amdgcn_exp2f(ea[1]) };
    sp[20] += ex;
}

// ---- main kernel: one block per (batch, pass); ring-6 of fp16 16-row chunks ----
__global__ __launch_bounds__(256, 2)
void knrm_main(const int* __restrict__ q1, const int* __restrict__ d1,
               const int* __restrict__ q2, const int* __restrict__ d2,
               const unsigned short* __restrict__ tab,
               float* __restrict__ kmws)
{
    __shared__ unsigned short buf[6][16*128];  // 4KB each (fp16 rows)
    __shared__ int   sh_ids[256];
    __shared__ float KMpart[4][21];

    const int tid = threadIdx.x;
    const int bb  = blockIdx.x >> 1;
    const int p   = blockIdx.x & 1;
    const int w   = tid >> 6;     // wave 0..3 -> q rows 16w..16w+15
    const int l   = tid & 63;
    const int lr  = l & 15;       // MFMA row (A) / col=q (B,C)
    const int lh  = l >> 4;       // k-group

    const int* qids = (p == 0 ? q1 : q2) + bb * 64;
    const int* dids = (p == 0 ? d1 : d2) + bb * 256;

    sh_ids[tid] = dids[tid];
    stage_q16(tab, qids, buf[w], w, l);              // buf w = wave w's q rows
    asm volatile("s_waitcnt vmcnt(0) lgkmcnt(0)" ::: "memory");
    __builtin_amdgcn_s_barrier();                    // q + sh_ids visible to all

    // Hoist B (q-side) fragments to registers for the whole pass.
    f16x8 Bq[4];
    #pragma unroll
    for (int ks = 0; ks < 4; ks++) {
        const int off = lr*128 + (((ks*4 + lh) ^ lr) << 3);
        Bq[ks] = *reinterpret_cast<const f16x8*>(&buf[w][off]);
    }
    asm volatile("s_waitcnt lgkmcnt(0)" ::: "memory");   // my B reads landed
    __builtin_amdgcn_s_barrier();                        // all waves done reading q

    f32x2 sp[21];
    #pragma unroll
    for (int i = 0; i < 21; i++) sp[i] = (f32x2){0.f, 0.f};

    // Prologue: chunks 0..4 in flight (5 loads/wave outstanding).
    stage_d16(tab, sh_ids, 0,  buf[0], w, l);
    stage_d16(tab, sh_ids, 16, buf[1], w, l);
    stage_d16(tab, sh_ids, 32, buf[2], w, l);
    stage_d16(tab, sh_ids, 48, buf[3], w, l);
    stage_d16(tab, sh_ids, 64, buf[4], w, l);

    for (int c = 0; c < 16; c++) {
        // Wait for my chunk-c load only (up to 4 later chunks stay in flight).
        if (c <= 11)      asm volatile("s_waitcnt vmcnt(4)" ::: "memory");
        else if (c == 12) asm volatile("s_waitcnt vmcnt(3)" ::: "memory");
        else if (c == 13) asm volatile("s_waitcnt vmcnt(2)" ::: "memory");
        else if (c == 14) asm volatile("s_waitcnt vmcnt(1)" ::: "memory");
        else              asm volatile("s_waitcnt vmcnt(0)" ::: "memory");
        __builtin_amdgcn_s_barrier();                // chunk c staged by all waves
        // (single barrier: refill slot (c+5)%6 == (c-1)%6 was freed by every
        //  wave before it passed THIS barrier)

        const unsigned short* cb = buf[c % 6];
        f32x4 C = {0.f,0.f,0.f,0.f};
        #pragma unroll
        for (int ks = 0; ks < 4; ks++) {
            const int o = lr*128 + (((ks*4 + lh) ^ lr) << 3);
            const f16x8 A = *reinterpret_cast<const f16x8*>(cb + o);
            C = __builtin_amdgcn_mfma_f32_16x16x32_f16(A, Bq[ks], C, 0, 0, 0);
        }
        apply_pair(C[0], C[1], sp);
        apply_pair(C[2], C[3], sp);

        if (c <= 10)                                 // refill freed slot with chunk c+5
            stage_d16(tab, sh_ids, (c + 5) * 16, buf[(c + 5) % 6], w, l);
    }

    // Reduction: packed halves + deferred constant, q-col sum (xor16,32) ->
    // log1p -> 16-group sum (xor1..8) -> per-wave partial KM.
    #pragma unroll
    for (int i = 0; i < 21; i++) {
        float s = (sp[i][0] + sp[i][1]) * KC[i];
        s += __shfl_xor(s, 16);
        s += __shfl_xor(s, 32);
        float t = log1pf(s);
        t += __shfl_xor(t, 1);
        t += __shfl_xor(t, 2);
        t += __shfl_xor(t, 4);
        t += __shfl_xor(t, 8);
        if (l == 0) KMpart[w][i] = t;
    }
    __syncthreads();
    if (tid < 21)
        kmws[blockIdx.x * 21 + tid] = KMpart[0][tid] + KMpart[1][tid]
                                    + KMpart[2][tid] + KMpart[3][tid];
}

// ---- tiny MLP kernel: one block per batch element ----
__global__ __launch_bounds__(64)
void mlp_kernel(const float* __restrict__ kmws,
                const float* __restrict__ W1, const float* __restrict__ b1,
                const float* __restrict__ W2, const float* __restrict__ b2,
                const float* __restrict__ W3, const float* __restrict__ b3,
                float* __restrict__ out)
{
    __shared__ float KMs[2][21], x1s[2][10], x2s[2][5];
    const int tid = threadIdx.x;
    const int bb  = blockIdx.x;
    if (tid < 42) KMs[tid / 21][tid % 21] = kmws[(bb * 2 + tid / 21) * 21 + (tid % 21)];
    __syncthreads();
    if (tid < 10) {
        for (int p = 0; p < 2; p++) {
            float acc = b1[tid];
            #pragma unroll
            for (int i = 0; i < 21; i++) acc = fmaf(fmaxf(KMs[p][i], 0.0f), W1[i*10 + tid], acc);
            x1s[p][tid] = acc;
        }
    }
    __syncthreads();
    if (tid < 5) {
        for (int p = 0; p < 2; p++) {
            float acc = b2[tid];
            #pragma unroll
            for (int i = 0; i < 10; i++) acc = fmaf(fmaxf(x1s[p][i], 0.0f), W2[i*5 + tid], acc);
            x2s[p][tid] = acc;
        }
    }
    __syncthreads();
    if (tid == 0) {
        float lv[2];
        for (int p = 0; p < 2; p++) {
            float acc = b3[0];
            #pragma unroll
            for (int i = 0; i < 5; i++) acc = fmaf(fmaxf(x2s[p][i], 0.0f), W3[i], acc);
            lv[p] = acc;
        }
        out[bb] = 1.0f / (1.0f + expf(lv[1] - lv[0]));   // sigmoid(l1 - l2)
    }
}

// ---- fallback (ws too small): self-contained f32-gather kernel (bf16-split) ----
typedef __attribute__((ext_vector_type(8))) short bf16x8;
__device__ __forceinline__ unsigned short f2bf(float f) {
    unsigned u = __float_as_uint(f);
    u += 0x7fffu + ((u >> 16) & 1u);
    return (unsigned short)(u >> 16);
}
__device__ __forceinline__ float bf2f(unsigned short h) {
    return __uint_as_float(((unsigned)h) << 16);
}
__device__ __forceinline__ void stage_f32(const float* __restrict__ emb,
                                          const int* __restrict__ ids,
                                          unsigned short* __restrict__ hi,
                                          unsigned short* __restrict__ lo,
                                          int tid)
{
    const int lg = tid >> 5;
    const int ln = tid & 31;
    #pragma unroll
    for (int i = 0; i < 4; i++) {
        const int row = i * 8 + lg;
        const int id  = ids[row];
        const float4 v = *reinterpret_cast<const float4*>(emb + (size_t)id * 128 + ln * 4);
        float ss = v.x*v.x + v.y*v.y + v.z*v.z + v.w*v.w;
        #pragma unroll
        for (int m = 16; m >= 1; m >>= 1) ss += __shfl_xor(ss, m);
        const float rn = 1.0f / (sqrtf(ss) + 1e-13f);
        const float f0 = v.x*rn, f1 = v.y*rn, f2 = v.z*rn, f3 = v.w*rn;
        const unsigned short h0 = f2bf(f0), h1 = f2bf(f1), h2 = f2bf(f2), h3 = f2bf(f3);
        const unsigned short g0 = f2bf(f0 - bf2f(h0)), g1 = f2bf(f1 - bf2f(h1));
        const unsigned short g2 = f2bf(f2 - bf2f(h2)), g3 = f2bf(f3 - bf2f(h3));
        const int off = row*128 + (((ln >> 1) ^ (row & 15)) << 3) + ((ln & 1) << 2);
        *reinterpret_cast<uint2*>(hi + off) =
            make_uint2((unsigned)h0 | ((unsigned)h1 << 16), (unsigned)h2 | ((unsigned)h3 << 16));
        *reinterpret_cast<uint2*>(lo + off) =
            make_uint2((unsigned)g0 | ((unsigned)g1 << 16), (unsigned)g2 | ((unsigned)g3 << 16));
    }
}
#define MFMB(a, b, c) __builtin_amdgcn_mfma_f32_16x16x32_bf16((a), (b), (c), 0, 0, 0)

__global__ __launch_bounds__(256, 2)
void knrm_fallback(const int* __restrict__ q1, const int* __restrict__ d1,
                   const int* __restrict__ q2, const int* __restrict__ d2,
                   const float* __restrict__ emb,
                   const float* __restrict__ W1, const float* __restrict__ b1,
                   const float* __restrict__ W2, const float* __restrict__ b2,
                   const float* __restrict__ W3, const float* __restrict__ b3,
                   float* __restrict__ out)
{
    __shared__ unsigned short bh[2][32*128], bl[2][32*128];
    __shared__ float KMpart[2][4][21];
    __shared__ float x1s[2][10], x2s[2][5];
    const int tid = threadIdx.x;
    const int bb  = blockIdx.x;
    const int w   = tid >> 6;
    const int l   = tid & 63;
    const int lr  = l & 15;
    const int lh  = l >> 4;

    for (int p = 0; p < 2; p++) {
        const int* qids = (p == 0 ? q1 : q2) + bb * 64;
        const int* dids = (p == 0 ? d1 : d2) + bb * 256;
        stage_f32(emb, qids,      bh[0], bl[0], tid);
        stage_f32(emb, qids + 32, bh[1], bl[1], tid);
        __syncthreads();
        bf16x8 Bh[4], Bl[4];
        const int qb = w >> 1;
        const int qr = (w * 16 + lr) & 31;
        #pragma unroll
        for (int ks = 0; ks < 4; ks++) {
            const int off = qr*128 + (((ks*4 + lh) ^ lr) << 3);
            Bh[ks] = *reinterpret_cast<const bf16x8*>(&bh[qb][off]);
            Bl[ks] = *reinterpret_cast<const bf16x8*>(&bl[qb][off]);
        }
        __syncthreads();
        f32x2 sp[21];
        #pragma unroll
        for (int i = 0; i < 21; i++) sp[i] = (f32x2){0.f, 0.f};
        for (int c = 0; c < 8; c++) {
            stage_f32(emb, dids + c * 32, bh[c & 1], bl[c & 1], tid);
            __syncthreads();
            const unsigned short* ch = bh[c & 1];
            const unsigned short* cl = bl[c & 1];
            f32x4 C0 = {0.f,0.f,0.f,0.f}, C1 = {0.f,0.f,0.f,0.f};
            #pragma unroll
            for (int ks = 0; ks < 4; ks++) {
                const int o0 = lr*128        + (((ks*4 + lh) ^ lr) << 3);
                const int o1 = (16 + lr)*128 + (((ks*4 + lh) ^ lr) << 3);
                const bf16x8 A0h = *reinterpret_cast<const bf16x8*>(ch + o0);
                const bf16x8 A0l = *reinterpret_cast<const bf16x8*>(cl + o0);
                const bf16x8 A1h = *reinterpret_cast<const bf16x8*>(ch + o1);
                const bf16x8 A1l = *reinterpret_cast<const bf16x8*>(cl + o1);
                C0 = MFMB(A0h, Bh[ks], C0); C1 = MFMB(A1h, Bh[ks], C1);
                C0 = MFMB(A0h, Bl[ks], C0); C1 = MFMB(A1h, Bl[ks], C1);
                C0 = MFMB(A0l, Bh[ks], C0); C1 = MFMB(A1l, Bh[ks], C1);
            }
            apply_pair(C0[0], C0[1], sp); apply_pair(C0[2], C0[3], sp);
            apply_pair(C1[0], C1[1], sp); apply_pair(C1[2], C1[3], sp);
            __syncthreads();
        }
        #pragma unroll
        for (int i = 0; i < 21; i++) {
            float s = (sp[i][0] + sp[i][1]) * KC[i];
            s += __shfl_xor(s, 16);
            s += __shfl_xor(s, 32);
            float t = log1pf(s);
            t += __shfl_xor(t, 1);
            t += __shfl_xor(t, 2);
            t += __shfl_xor(t, 4);
            t += __shfl_xor(t, 8);
            if (l == 0) KMpart[p][w][i] = t;
        }
    }
    __syncthreads();
    if (tid < 10) {
        for (int p = 0; p < 2; p++) {
            float acc = b1[tid];
            #pragma unroll
            for (int i = 0; i < 21; i++) {
                const float km = KMpart[p][0][i] + KMpart[p][1][i]
                               + KMpart[p][2][i] + KMpart[p][3][i];
                acc = fmaf(fmaxf(km, 0.0f), W1[i*10 + tid], acc);
            }
            x1s[p][tid] = acc;
        }
    }
    __syncthreads();
    if (tid < 5) {
        for (int p = 0; p < 2; p++) {
            float acc = b2[tid];
            #pragma unroll
            for (int i = 0; i < 10; i++) acc = fmaf(fmaxf(x1s[p][i], 0.0f), W2[i*5 + tid], acc);
            x2s[p][tid] = acc;
        }
    }
    __syncthreads();
    if (tid == 0) {
        float lv[2];
        for (int p = 0; p < 2; p++) {
            float acc = b3[0];
            #pragma unroll
            for (int i = 0; i < 5; i++) acc = fmaf(fmaxf(x2s[p][i], 0.0f), W3[i], acc);
            lv[p] = acc;
        }
        out[bb] = 1.0f / (1.0f + expf(lv[1] - lv[0]));
    }
}

extern "C" void kernel_launch(void* const* d_in, const int* in_sizes, int n_in,
                              void* d_out, int out_size, void* d_ws, size_t ws_size,
                              hipStream_t stream)
{
    const int*   q1  = (const int*)  d_in[0];
    const int*   d1  = (const int*)  d_in[1];
    const int*   q2  = (const int*)  d_in[2];
    const int*   d2  = (const int*)  d_in[3];
    const float* emb = (const float*)d_in[4];
    const float* W1  = (const float*)d_in[5];
    const float* b1  = (const float*)d_in[6];
    const float* W2  = (const float*)d_in[7];
    const float* b2  = (const float*)d_in[8];
    const float* W3  = (const float*)d_in[9];
    const float* b3  = (const float*)d_in[10];
    float* out = (float*)d_out;
    (void)n_in;

    const int    vocab = in_sizes[4] / 128;
    const size_t tabsz = (size_t)vocab * 128 * 2;        // fp16 table bytes
    const size_t kmsz  = (size_t)out_size * 2 * 21 * 4;  // KM partials
    const size_t need  = tabsz + kmsz;

    if (ws_size >= need) {
        unsigned short* tab = (unsigned short*)d_ws;
        float* kmws = (float*)((char*)d_ws + tabsz);
        norm_split_kernel<<<(vocab + 7) / 8, 256, 0, stream>>>(emb, tab, vocab);
        knrm_main<<<out_size * 2, 256, 0, stream>>>(q1, d1, q2, d2, tab, kmws);
        mlp_kernel<<<out_size, 64, 0, stream>>>(kmws, W1, b1, W2, b2, W3, b3, out);
    } else {
        knrm_fallback<<<out_size, 256, 0, stream>>>(q1, d1, q2, d2, emb,
                                                    W1, b1, W2, b2, W3, b3, out);
    }
}

// Round 16
// 101.276 us; speedup vs baseline: 1.1295x; 1.0323x over previous
//
#include <hip/hip_runtime.h>

// KNRM forward, MI355X (gfx950). R15.
// R8-R14 consolidated: wall pinned 93-110us across occupancy/bytes/granule/
// queue/barrier/op-count levers. Remaining critical path: per-chunk serial
// ds_read -> MFMA -> apply. R15: (1) defer-apply pipeline -- chunk c's MFMA
// result C is applied during iteration c+1, hiding LDS+MFMA latency under the
// previous chunk's ~600cy apply VALU; (2) exact-match skip -- the sigma=1e-3
// exp underflows to EXACTLY 0 for m<=0.985, so gate it behind wave-uniform
// __any(cmax>0.98) (fires ~4% of chunks; bit-exact otherwise). -25% trans.
// Everything else identical to R14 (passing, 93us main): fp16 table, ring-6
// of 16-row chunks, counted vmcnt, single barrier/chunk, deferred KC consts.

typedef __attribute__((ext_vector_type(8))) _Float16 f16x8;
typedef __attribute__((ext_vector_type(4))) float f32x4;
typedef __attribute__((ext_vector_type(2))) float f32x2;

__device__ __forceinline__ unsigned short h2s(_Float16 h) {
    return __builtin_bit_cast(unsigned short, h);
}

// ---- precompute: normalized fp16 table, row-major [vocab][128] (256B/row) ----
__global__ __launch_bounds__(256)
void norm_split_kernel(const float* __restrict__ emb,
                       unsigned short* __restrict__ tab, int vocab)
{
    const int row = blockIdx.x * 8 + (threadIdx.x >> 5);
    if (row >= vocab) return;
    const int ln = threadIdx.x & 31;
    const float4 v = *reinterpret_cast<const float4*>(emb + (size_t)row * 128 + ln * 4);
    float ss = v.x*v.x + v.y*v.y + v.z*v.z + v.w*v.w;
    #pragma unroll
    for (int m = 16; m >= 1; m >>= 1) ss += __shfl_xor(ss, m);   // 32-lane row reduce
    const float rn = 1.0f / (sqrtf(ss) + 1e-13f);                // reference eps
    const unsigned short h0 = h2s((_Float16)(v.x * rn));
    const unsigned short h1 = h2s((_Float16)(v.y * rn));
    const unsigned short h2 = h2s((_Float16)(v.z * rn));
    const unsigned short h3 = h2s((_Float16)(v.w * rn));
    *reinterpret_cast<uint2*>(tab + (size_t)row * 128 + ln * 4) =
        make_uint2((unsigned)h0 | ((unsigned)h1 << 16), (unsigned)h2 | ((unsigned)h3 << 16));
}

// ---- global_load_lds: 16B/lane, linear LDS dest (base + lane*16) ----
__device__ __forceinline__ void glds16(const unsigned short* g, unsigned short* l) {
    __builtin_amdgcn_global_load_lds((const __attribute__((address_space(1))) void*)g,
                                     (__attribute__((address_space(3))) void*)l, 16, 0, 0);
}

// Stage one 16-row chunk (wave w: rows 4w..4w+3 -> ONE glds16).
// Swizzle folded into per-lane GLOBAL address: slot s holds group s^r.
__device__ __forceinline__ void stage_d16(const unsigned short* __restrict__ tab,
                                          const int* __restrict__ ids, int base,
                                          unsigned short* __restrict__ db,
                                          int w, int l)
{
    const int r   = 4*w + (l >> 4);                  // buffer row 0..15
    const int id  = ids[base + r];                   // LDS broadcast read
    const int gsw = ((l & 15) ^ r) << 3;             // swizzled elem offset in row
    glds16(tab + (size_t)id * 128 + gsw, db + 4*w * 128);
}

// Stage q: wave w fills one ring buffer with its 16 q rows (4 glds16).
__device__ __forceinline__ void stage_q16(const unsigned short* __restrict__ tab,
                                          const int* __restrict__ qids,
                                          unsigned short* __restrict__ db,
                                          int w, int l)
{
    #pragma unroll
    for (int j = 0; j < 4; j++) {
        const int r   = 4*j + (l >> 4);
        const int id  = qids[16*w + r];
        const int gsw = ((l & 15) ^ r) << 3;
        glds16(tab + (size_t)id * 128 + gsw, db + 4*j * 128);
    }
}

// Deferred ladder constants (applied once per lane at reduction):
// sp[10+j] holds Sum t0*R^j  -> true k-sum = sp * e^{-j(j+1)/2}
// sp[10-j] holds Sum t0*R^-j -> true k-sum = sp * e^{-j(j-1)/2}
__device__ __constant__ float KC[21] = {
    2.8625185805e-20f, 2.3195228302e-16f, 6.9144001069e-13f, 7.5825604279e-10f,
    3.0590232050e-7f,  4.5399929762e-5f,  2.4787521767e-3f,  4.9787068368e-2f,
    3.6787944117e-1f,  1.0f,              1.0f,              3.6787944117e-1f,
    4.9787068368e-2f,  2.4787521767e-3f,  4.5399929762e-5f,  3.0590232050e-7f,
    7.5825604279e-10f, 6.9144001069e-13f, 2.3195228302e-16f, 2.8625185805e-20f,
    1.0f
};

// Gaussian power-sum ladder for an element PAIR (no exact-match term).
__device__ __forceinline__ void apply_pair_g(float m0, float m1, f32x2 (&sp)[21]) {
    const f32x2 m2 = {m0, m1};
    const f32x2 dm = m2 - 0.05f;
    const f32x2 ta = (dm * dm) * -72.13475204444817f;            // -50*log2e*(m-.05)^2
    const f32x2 x2 = m2 * 14.426950408889634f;                   // 10*log2e*m
    const f32x2 t0 = { __builtin_amdgcn_exp2f(ta[0]), __builtin_amdgcn_exp2f(ta[1]) };
    const f32x2 R  = { __builtin_amdgcn_exp2f(x2[0]), __builtin_amdgcn_exp2f(x2[1]) };
    const f32x2 Ri = { __builtin_amdgcn_exp2f(-x2[0]), __builtin_amdgcn_exp2f(-x2[1]) };
    sp[10] += t0;
    f32x2 tu = t0;
    tu *= R;  sp[11] += tu;
    tu *= R;  sp[12] += tu;
    tu *= R;  sp[13] += tu;
    tu *= R;  sp[14] += tu;
    tu *= R;  sp[15] += tu;
    tu *= R;  sp[16] += tu;
    tu *= R;  sp[17] += tu;
    tu *= R;  sp[18] += tu;
    tu *= R;  sp[19] += tu;
    f32x2 td = t0;
    td *= Ri; sp[9] += td;
    td *= Ri; sp[8] += td;
    td *= Ri; sp[7] += td;
    td *= Ri; sp[6] += td;
    td *= Ri; sp[5] += td;
    td *= Ri; sp[4] += td;
    td *= Ri; sp[3] += td;
    td *= Ri; sp[2] += td;
    td *= Ri; sp[1] += td;
    td *= Ri; sp[0] += td;
}

// Full chunk apply: 2 packed Gaussian ladders + wave-uniform-guarded exact-match.
// exp2(-721347.5*(m-1)^2) == 0 exactly for m <= 0.985 (|arg|>149 -> underflow),
// so skipping when no lane exceeds 0.98 is BIT-EXACT.
__device__ __forceinline__ void apply_chunk(const f32x4& C, f32x2 (&sp)[21]) {
    apply_pair_g(C[0], C[1], sp);
    apply_pair_g(C[2], C[3], sp);
    const float cmax = fmaxf(fmaxf(C[0], C[1]), fmaxf(C[2], C[3]));
    if (__any(cmax > 0.98f)) {
        const f32x2 e0 = { C[0] - 1.0f, C[1] - 1.0f };
        const f32x2 e1 = { C[2] - 1.0f, C[3] - 1.0f };
        const f32x2 a0 = (e0 * e0) * -721347.5204444817f;
        const f32x2 a1 = (e1 * e1) * -721347.5204444817f;
        const f32x2 ex = { __builtin_amdgcn_exp2f(a0[0]) + __builtin_amdgcn_exp2f(a1[0]),
                           __builtin_amdgcn_exp2f(a0[1]) + __builtin_amdgcn_exp2f(a1[1]) };
        sp[20] += ex;
    }
}

// ---- main kernel: one block per (batch, pass); ring-6, defer-apply pipeline ----
__global__ __launch_bounds__(256, 2)
void knrm_main(const int* __restrict__ q1, const int* __restrict__ d1,
               const int* __restrict__ q2, const int* __restrict__ d2,
               const unsigned short* __restrict__ tab,
               float* __restrict__ kmws)
{
    __shared__ unsigned short buf[6][16*128];  // 4KB each (fp16 rows)
    __shared__ int   sh_ids[256];
    __shared__ float KMpart[4][21];

    const int tid = threadIdx.x;
    const int bb  = blockIdx.x >> 1;
    const int p   = blockIdx.x & 1;
    const int w   = tid >> 6;     // wave 0..3 -> q rows 16w..16w+15
    const int l   = tid & 63;
    const int lr  = l & 15;       // MFMA row (A) / col=q (B,C)
    const int lh  = l >> 4;       // k-group

    const int* qids = (p == 0 ? q1 : q2) + bb * 64;
    const int* dids = (p == 0 ? d1 : d2) + bb * 256;

    sh_ids[tid] = dids[tid];
    stage_q16(tab, qids, buf[w], w, l);              // buf w = wave w's q rows
    asm volatile("s_waitcnt vmcnt(0) lgkmcnt(0)" ::: "memory");
    __builtin_amdgcn_s_barrier();                    // q + sh_ids visible to all

    // Hoist B (q-side) fragments to registers for the whole pass.
    f16x8 Bq[4];
    #pragma unroll
    for (int ks = 0; ks < 4; ks++) {
        const int off = lr*128 + (((ks*4 + lh) ^ lr) << 3);
        Bq[ks] = *reinterpret_cast<const f16x8*>(&buf[w][off]);
    }
    asm volatile("s_waitcnt lgkmcnt(0)" ::: "memory");   // my B reads landed
    __builtin_amdgcn_s_barrier();                        // all waves done reading q

    f32x2 sp[21];
    #pragma unroll
    for (int i = 0; i < 21; i++) sp[i] = (f32x2){0.f, 0.f};

    // Prologue: chunks 0..4 in flight (5 loads/wave outstanding).
    stage_d16(tab, sh_ids, 0,  buf[0], w, l);
    stage_d16(tab, sh_ids, 16, buf[1], w, l);
    stage_d16(tab, sh_ids, 32, buf[2], w, l);
    stage_d16(tab, sh_ids, 48, buf[3], w, l);
    stage_d16(tab, sh_ids, 64, buf[4], w, l);

    // Chunk 0: MFMA only (its apply is deferred into iteration 1).
    f32x4 Cp = {0.f,0.f,0.f,0.f};
    asm volatile("s_waitcnt vmcnt(4)" ::: "memory");
    __builtin_amdgcn_s_barrier();
    #pragma unroll
    for (int ks = 0; ks < 4; ks++) {
        const int o = lr*128 + (((ks*4 + lh) ^ lr) << 3);
        const f16x8 A = *reinterpret_cast<const f16x8*>(buf[0] + o);
        Cp = __builtin_amdgcn_mfma_f32_16x16x32_f16(A, Bq[ks], Cp, 0, 0, 0);
    }
    stage_d16(tab, sh_ids, 80, buf[5], w, l);        // refill slot 5 (chunk 5)

    for (int c = 1; c < 16; c++) {
        // Wait for my chunk-c load only (up to 4 later chunks stay in flight).
        if (c <= 11)      asm volatile("s_waitcnt vmcnt(4)" ::: "memory");
        else if (c == 12) asm volatile("s_waitcnt vmcnt(3)" ::: "memory");
        else if (c == 13) asm volatile("s_waitcnt vmcnt(2)" ::: "memory");
        else if (c == 14) asm volatile("s_waitcnt vmcnt(1)" ::: "memory");
        else              asm volatile("s_waitcnt vmcnt(0)" ::: "memory");
        __builtin_amdgcn_s_barrier();                // chunk c staged by all waves
        // (single barrier: refill slot (c+5)%6 == (c-1)%6 was freed -- every
        //  wave's ds_reads of chunk c-1 completed via its MFMA data-dep before
        //  it passed THIS barrier)

        const unsigned short* cb = buf[c % 6];
        f32x4 C = {0.f,0.f,0.f,0.f};
        #pragma unroll
        for (int ks = 0; ks < 4; ks++) {
            const int o = lr*128 + (((ks*4 + lh) ^ lr) << 3);
            const f16x8 A = *reinterpret_cast<const f16x8*>(cb + o);
            C = __builtin_amdgcn_mfma_f32_16x16x32_f16(A, Bq[ks], C, 0, 0, 0);
        }
        if (c <= 10)                                 // refill freed slot with chunk c+5
            stage_d16(tab, sh_ids, (c + 5) * 16, buf[(c + 5) % 6], w, l);

        apply_chunk(Cp, sp);                         // apply PREVIOUS chunk: hides
        Cp = C;                                      // this chunk's MFMA latency
    }
    apply_chunk(Cp, sp);                             // epilogue: chunk 15

    // Reduction: packed halves + deferred constant, q-col sum (xor16,32) ->
    // log1p -> 16-group sum (xor1..8) -> per-wave partial KM.
    #pragma unroll
    for (int i = 0; i < 21; i++) {
        float s = (sp[i][0] + sp[i][1]) * KC[i];
        s += __shfl_xor(s, 16);
        s += __shfl_xor(s, 32);
        float t = log1pf(s);
        t += __shfl_xor(t, 1);
        t += __shfl_xor(t, 2);
        t += __shfl_xor(t, 4);
        t += __shfl_xor(t, 8);
        if (l == 0) KMpart[w][i] = t;
    }
    __syncthreads();
    if (tid < 21)
        kmws[blockIdx.x * 21 + tid] = KMpart[0][tid] + KMpart[1][tid]
                                    + KMpart[2][tid] + KMpart[3][tid];
}

// ---- tiny MLP kernel: one block per batch element ----
__global__ __launch_bounds__(64)
void mlp_kernel(const float* __restrict__ kmws,
                const float* __restrict__ W1, const float* __restrict__ b1,
                const float* __restrict__ W2, const float* __restrict__ b2,
                const float* __restrict__ W3, const float* __restrict__ b3,
                float* __restrict__ out)
{
    __shared__ float KMs[2][21], x1s[2][10], x2s[2][5];
    const int tid = threadIdx.x;
    const int bb  = blockIdx.x;
    if (tid < 42) KMs[tid / 21][tid % 21] = kmws[(bb * 2 + tid / 21) * 21 + (tid % 21)];
    __syncthreads();
    if (tid < 10) {
        for (int p = 0; p < 2; p++) {
            float acc = b1[tid];
            #pragma unroll
            for (int i = 0; i < 21; i++) acc = fmaf(fmaxf(KMs[p][i], 0.0f), W1[i*10 + tid], acc);
            x1s[p][tid] = acc;
        }
    }
    __syncthreads();
    if (tid < 5) {
        for (int p = 0; p < 2; p++) {
            float acc = b2[tid];
            #pragma unroll
            for (int i = 0; i < 10; i++) acc = fmaf(fmaxf(x1s[p][i], 0.0f), W2[i*5 + tid], acc);
            x2s[p][tid] = acc;
        }
    }
    __syncthreads();
    if (tid == 0) {
        float lv[2];
        for (int p = 0; p < 2; p++) {
            float acc = b3[0];
            #pragma unroll
            for (int i = 0; i < 5; i++) acc = fmaf(fmaxf(x2s[p][i], 0.0f), W3[i], acc);
            lv[p] = acc;
        }
        out[bb] = 1.0f / (1.0f + expf(lv[1] - lv[0]));   // sigmoid(l1 - l2)
    }
}

// ---- fallback (ws too small): self-contained f32-gather kernel (bf16-split) ----
typedef __attribute__((ext_vector_type(8))) short bf16x8;
__device__ __forceinline__ unsigned short f2bf(float f) {
    unsigned u = __float_as_uint(f);
    u += 0x7fffu + ((u >> 16) & 1u);
    return (unsigned short)(u >> 16);
}
__device__ __forceinline__ float bf2f(unsigned short h) {
    return __uint_as_float(((unsigned)h) << 16);
}
__device__ __forceinline__ void stage_f32(const float* __restrict__ emb,
                                          const int* __restrict__ ids,
                                          unsigned short* __restrict__ hi,
                                          unsigned short* __restrict__ lo,
                                          int tid)
{
    const int lg = tid >> 5;
    const int ln = tid & 31;
    #pragma unroll
    for (int i = 0; i < 4; i++) {
        const int row = i * 8 + lg;
        const int id  = ids[row];
        const float4 v = *reinterpret_cast<const float4*>(emb + (size_t)id * 128 + ln * 4);
        float ss = v.x*v.x + v.y*v.y + v.z*v.z + v.w*v.w;
        #pragma unroll
        for (int m = 16; m >= 1; m >>= 1) ss += __shfl_xor(ss, m);
        const float rn = 1.0f / (sqrtf(ss) + 1e-13f);
        const float f0 = v.x*rn, f1 = v.y*rn, f2 = v.z*rn, f3 = v.w*rn;
        const unsigned short h0 = f2bf(f0), h1 = f2bf(f1), h2 = f2bf(f2), h3 = f2bf(f3);
        const unsigned short g0 = f2bf(f0 - bf2f(h0)), g1 = f2bf(f1 - bf2f(h1));
        const unsigned short g2 = f2bf(f2 - bf2f(h2)), g3 = f2bf(f3 - bf2f(h3));
        const int off = row*128 + (((ln >> 1) ^ (row & 15)) << 3) + ((ln & 1) << 2);
        *reinterpret_cast<uint2*>(hi + off) =
            make_uint2((unsigned)h0 | ((unsigned)h1 << 16), (unsigned)h2 | ((unsigned)h3 << 16));
        *reinterpret_cast<uint2*>(lo + off) =
            make_uint2((unsigned)g0 | ((unsigned)g1 << 16), (unsigned)g2 | ((unsigned)g3 << 16));
    }
}
#define MFMB(a, b, c) __builtin_amdgcn_mfma_f32_16x16x32_bf16((a), (b), (c), 0, 0, 0)

__global__ __launch_bounds__(256, 2)
void knrm_fallback(const int* __restrict__ q1, const int* __restrict__ d1,
                   const int* __restrict__ q2, const int* __restrict__ d2,
                   const float* __restrict__ emb,
                   const float* __restrict__ W1, const float* __restrict__ b1,
                   const float* __restrict__ W2, const float* __restrict__ b2,
                   const float* __restrict__ W3, const float* __restrict__ b3,
                   float* __restrict__ out)
{
    __shared__ unsigned short bh[2][32*128], bl[2][32*128];
    __shared__ float KMpart[2][4][21];
    __shared__ float x1s[2][10], x2s[2][5];
    const int tid = threadIdx.x;
    const int bb  = blockIdx.x;
    const int w   = tid >> 6;
    const int l   = tid & 63;
    const int lr  = l & 15;
    const int lh  = l >> 4;

    for (int p = 0; p < 2; p++) {
        const int* qids = (p == 0 ? q1 : q2) + bb * 64;
        const int* dids = (p == 0 ? d1 : d2) + bb * 256;
        stage_f32(emb, qids,      bh[0], bl[0], tid);
        stage_f32(emb, qids + 32, bh[1], bl[1], tid);
        __syncthreads();
        bf16x8 Bh[4], Bl[4];
        const int qb = w >> 1;
        const int qr = (w * 16 + lr) & 31;
        #pragma unroll
        for (int ks = 0; ks < 4; ks++) {
            const int off = qr*128 + (((ks*4 + lh) ^ lr) << 3);
            Bh[ks] = *reinterpret_cast<const bf16x8*>(&bh[qb][off]);
            Bl[ks] = *reinterpret_cast<const bf16x8*>(&bl[qb][off]);
        }
        __syncthreads();
        f32x2 sp[21];
        #pragma unroll
        for (int i = 0; i < 21; i++) sp[i] = (f32x2){0.f, 0.f};
        for (int c = 0; c < 8; c++) {
            stage_f32(emb, dids + c * 32, bh[c & 1], bl[c & 1], tid);
            __syncthreads();
            const unsigned short* ch = bh[c & 1];
            const unsigned short* cl = bl[c & 1];
            f32x4 C0 = {0.f,0.f,0.f,0.f}, C1 = {0.f,0.f,0.f,0.f};
            #pragma unroll
            for (int ks = 0; ks < 4; ks++) {
                const int o0 = lr*128        + (((ks*4 + lh) ^ lr) << 3);
                const int o1 = (16 + lr)*128 + (((ks*4 + lh) ^ lr) << 3);
                const bf16x8 A0h = *reinterpret_cast<const bf16x8*>(ch + o0);
                const bf16x8 A0l = *reinterpret_cast<const bf16x8*>(cl + o0);
                const bf16x8 A1h = *reinterpret_cast<const bf16x8*>(ch + o1);
                const bf16x8 A1l = *reinterpret_cast<const bf16x8*>(cl + o1);
                C0 = MFMB(A0h, Bh[ks], C0); C1 = MFMB(A1h, Bh[ks], C1);
                C0 = MFMB(A0h, Bl[ks], C0); C1 = MFMB(A1h, Bl[ks], C1);
                C0 = MFMB(A0l, Bh[ks], C0); C1 = MFMB(A1l, Bh[ks], C1);
            }
            apply_chunk(C0, sp);
            apply_chunk(C1, sp);
            __syncthreads();
        }
        #pragma unroll
        for (int i = 0; i < 21; i++) {
            float s = (sp[i][0] + sp[i][1]) * KC[i];
            s += __shfl_xor(s, 16);
            s += __shfl_xor(s, 32);
            float t = log1pf(s);
            t += __shfl_xor(t, 1);
            t += __shfl_xor(t, 2);
            t += __shfl_xor(t, 4);
            t += __shfl_xor(t, 8);
            if (l == 0) KMpart[p][w][i] = t;
        }
    }
    __syncthreads();
    if (tid < 10) {
        for (int p = 0; p < 2; p++) {
            float acc = b1[tid];
            #pragma unroll
            for (int i = 0; i < 21; i++) {
                const float km = KMpart[p][0][i] + KMpart[p][1][i]
                               + KMpart[p][2][i] + KMpart[p][3][i];
                acc = fmaf(fmaxf(km, 0.0f), W1[i*10 + tid], acc);
            }
            x1s[p][tid] = acc;
        }
    }
    __syncthreads();
    if (tid < 5) {
        for (int p = 0; p < 2; p++) {
            float acc = b2[tid];
            #pragma unroll
            for (int i = 0; i < 10; i++) acc = fmaf(fmaxf(x1s[p][i], 0.0f), W2[i*5 + tid], acc);
            x2s[p][tid] = acc;
        }
    }
    __syncthreads();
    if (tid == 0) {
        float lv[2];
        for (int p = 0; p < 2; p++) {
            float acc = b3[0];
            #pragma unroll
            for (int i = 0; i < 5; i++) acc = fmaf(fmaxf(x2s[p][i], 0.0f), W3[i], acc);
            lv[p] = acc;
        }
        out[bb] = 1.0f / (1.0f + expf(lv[1] - lv[0]));
    }
}

extern "C" void kernel_launch(void* const* d_in, const int* in_sizes, int n_in,
                              void* d_out, int out_size, void* d_ws, size_t ws_size,
                              hipStream_t stream)
{
    const int*   q1  = (const int*)  d_in[0];
    const int*   d1  = (const int*)  d_in[1];
    const int*   q2  = (const int*)  d_in[2];
    const int*   d2  = (const int*)  d_in[3];
    const float* emb = (const float*)d_in[4];
    const float* W1  = (const float*)d_in[5];
    const float* b1  = (const float*)d_in[6];
    const float* W2  = (const float*)d_in[7];
    const float* b2  = (const float*)d_in[8];
    const float* W3  = (const float*)d_in[9];
    const float* b3  = (const float*)d_in[10];
    float* out = (float*)d_out;
    (void)n_in;

    const int    vocab = in_sizes[4] / 128;
    const size_t tabsz = (size_t)vocab * 128 * 2;        // fp16 table bytes
    const size_t kmsz  = (size_t)out_size * 2 * 21 * 4;  // KM partials
    const size_t need  = tabsz + kmsz;

    if (ws_size >= need) {
        unsigned short* tab = (unsigned short*)d_ws;
        float* kmws = (float*)((char*)d_ws + tabsz);
        norm_split_kernel<<<(vocab + 7) / 8, 256, 0, stream>>>(emb, tab, vocab);
        knrm_main<<<out_size * 2, 256, 0, stream>>>(q1, d1, q2, d2, tab, kmws);
        mlp_kernel<<<out_size, 64, 0, stream>>>(kmws, W1, b1, W2, b2, W3, b3, out);
    } else {
        knrm_fallback<<<out_size, 256, 0, stream>>>(q1, d1, q2, d2, emb,
                                                    W1, b1, W2, b2, W3, b3, out);
    }
}